// Round 1
// baseline (4474.965 us; speedup 1.0000x reference)
//
#include <hip/hip_runtime.h>

// HeteroRGCN on MI355X — fp32 VALU baseline.
// Pipeline (all on `stream`):
//   memset(acc_c,acc_m,cnt_c,cnt_m)
//   k128_node(card), k128_node(merch), k128_txn (gather + atomic scatter + counts)
//   lk_node(card), lk_node(merch), memset(acc), lk_txn
//   lk_node(card), lk_node(merch), lk_out     <- layer-2 segment means are dead code, skipped
// Counts are computed once in k128_txn and reused by both later layers (idx static).

#define LRELU(v) ((v) > 0.0f ? (v) : 0.01f * (v))

static constexpr int NTXN   = 1000000;
static constexpr int NCARD  = 500000;
static constexpr int NMERCH = 100000;

// ---------------- K=128 -> 16 node transform (card / merch), Y = X@W + b ----------------
__global__ __launch_bounds__(256) void k128_node(
    const float* __restrict__ X, const float* __restrict__ W,
    const float* __restrict__ b, float* __restrict__ Y, int R)
{
    __shared__ float xs[256 * 36];   // 256 rows x 32 k, stride 36 (pad -> conflict-free b128)
    __shared__ float ws[128 * 16];
    __shared__ float bs[16];
    const int tid = threadIdx.x;
    for (int i = tid; i < 2048; i += 256) ws[i] = W[i];
    if (tid < 16) bs[tid] = b[tid];
    const int row0 = blockIdx.x * 256;

    float acc[16];
#pragma unroll
    for (int n = 0; n < 16; n++) acc[n] = 0.0f;

#pragma unroll 1
    for (int kb = 0; kb < 128; kb += 32) {
        __syncthreads();
#pragma unroll
        for (int j = 0; j < 8; j++) {               // 2048 float4s / 256 thr = 8 each
            int f = tid + j * 256;
            int r = f >> 3, c = (f & 7) << 2;
            int gr = row0 + r;
            float4 v = make_float4(0.f, 0.f, 0.f, 0.f);
            if (gr < R) v = *(const float4*)(X + (size_t)gr * 128 + kb + c);
            *(float4*)(xs + r * 36 + c) = v;
        }
        __syncthreads();
        const float* xr = xs + tid * 36;
#pragma unroll
        for (int k = 0; k < 32; k += 4) {
            float4 x4 = *(const float4*)(xr + k);
#pragma unroll
            for (int n4 = 0; n4 < 16; n4 += 4) {
                float4 wa = *(const float4*)(ws + (kb + k + 0) * 16 + n4);
                float4 wb = *(const float4*)(ws + (kb + k + 1) * 16 + n4);
                float4 wc = *(const float4*)(ws + (kb + k + 2) * 16 + n4);
                float4 wd = *(const float4*)(ws + (kb + k + 3) * 16 + n4);
                acc[n4 + 0] += x4.x * wa.x + x4.y * wb.x + x4.z * wc.x + x4.w * wd.x;
                acc[n4 + 1] += x4.x * wa.y + x4.y * wb.y + x4.z * wc.y + x4.w * wd.y;
                acc[n4 + 2] += x4.x * wa.z + x4.y * wb.z + x4.z * wc.z + x4.w * wd.z;
                acc[n4 + 3] += x4.x * wa.w + x4.y * wb.w + x4.z * wc.w + x4.w * wd.w;
            }
        }
    }
    const int row = row0 + tid;
    if (row < R) {
        float* yp = Y + (size_t)row * 16;
#pragma unroll
        for (int n4 = 0; n4 < 16; n4 += 4) {
            float4 o = make_float4(acc[n4] + bs[n4], acc[n4 + 1] + bs[n4 + 1],
                                   acc[n4 + 2] + bs[n4 + 2], acc[n4 + 3] + bs[n4 + 3]);
            *(float4*)(yp + n4) = o;
        }
    }
}

// ---------------- K=128 txn transform: 3 matrices (self/tc/tm) + gather + scatter ----------------
__global__ __launch_bounds__(256) void k128_txn(
    const float* __restrict__ X, const float* __restrict__ W0, const float* __restrict__ b0,
    const float* __restrict__ tmp_c, const float* __restrict__ tmp_m,
    const int* __restrict__ card_idx, const int* __restrict__ merch_idx,
    float* __restrict__ h_t, float* __restrict__ acc_c, float* __restrict__ acc_m,
    float* __restrict__ cnt_c, float* __restrict__ cnt_m)
{
    __shared__ float xs[256 * 36];   // 36 KB
    __shared__ float ws[128 * 48];   // 24 KB: cols [0:16)=e2 self, [16:32)=e3 tc, [32:48)=e4 tm
    __shared__ float bs[48];
    const int tid = threadIdx.x;
    for (int i = tid; i < 128 * 48; i += 256) {
        int k = i / 48, c = i % 48, e = c >> 4, n = c & 15;
        ws[i] = W0[(size_t)(2 + e) * 2048 + k * 16 + n];
    }
    if (tid < 48) { int e = tid >> 4, n = tid & 15; bs[tid] = b0[(2 + e) * 16 + n]; }
    const int row0 = blockIdx.x * 256;

    float acc[48];
#pragma unroll
    for (int n = 0; n < 48; n++) acc[n] = 0.0f;

#pragma unroll 1
    for (int kb = 0; kb < 128; kb += 32) {
        __syncthreads();
#pragma unroll
        for (int j = 0; j < 8; j++) {
            int f = tid + j * 256;
            int r = f >> 3, c = (f & 7) << 2;
            int gr = row0 + r;
            float4 v = make_float4(0.f, 0.f, 0.f, 0.f);
            if (gr < NTXN) v = *(const float4*)(X + (size_t)gr * 128 + kb + c);
            *(float4*)(xs + r * 36 + c) = v;
        }
        __syncthreads();
        const float* xr = xs + tid * 36;
#pragma unroll 2
        for (int k = 0; k < 32; k += 4) {
            float4 x4 = *(const float4*)(xr + k);
#pragma unroll
            for (int n4 = 0; n4 < 48; n4 += 4) {
                float4 wa = *(const float4*)(ws + (kb + k + 0) * 48 + n4);
                float4 wb = *(const float4*)(ws + (kb + k + 1) * 48 + n4);
                float4 wc = *(const float4*)(ws + (kb + k + 2) * 48 + n4);
                float4 wd = *(const float4*)(ws + (kb + k + 3) * 48 + n4);
                acc[n4 + 0] += x4.x * wa.x + x4.y * wb.x + x4.z * wc.x + x4.w * wd.x;
                acc[n4 + 1] += x4.x * wa.y + x4.y * wb.y + x4.z * wc.y + x4.w * wd.y;
                acc[n4 + 2] += x4.x * wa.z + x4.y * wb.z + x4.z * wc.z + x4.w * wd.z;
                acc[n4 + 3] += x4.x * wa.w + x4.y * wb.w + x4.z * wc.w + x4.w * wd.w;
            }
        }
    }
    const int row = row0 + tid;
    if (row >= NTXN) return;
#pragma unroll
    for (int n = 0; n < 48; n++) acc[n] += bs[n];

    const int ci = card_idx[row], mi = merch_idx[row];
    const float* cp = tmp_c + (size_t)ci * 16;
    const float* mp = tmp_m + (size_t)mi * 16;
    float* hp = h_t + (size_t)row * 16;
#pragma unroll
    for (int n4 = 0; n4 < 16; n4 += 4) {
        float4 cv = *(const float4*)(cp + n4);
        float4 mv = *(const float4*)(mp + n4);
        float4 o = make_float4(acc[n4] + cv.x + mv.x, acc[n4 + 1] + cv.y + mv.y,
                               acc[n4 + 2] + cv.z + mv.z, acc[n4 + 3] + cv.w + mv.w);
        *(float4*)(hp + n4) = o;
    }
    float* ac = acc_c + (size_t)ci * 16;
    float* am = acc_m + (size_t)mi * 16;
#pragma unroll
    for (int n = 0; n < 16; n++) atomicAdd(ac + n, acc[16 + n]);
#pragma unroll
    for (int n = 0; n < 16; n++) atomicAdd(am + n, acc[32 + n]);
    atomicAdd(cnt_c + ci, 1.0f);
    atomicAdd(cnt_m + mi, 1.0f);
}

// ---------------- K=16 node transform: Y = lrelu(acc/max(cnt,1)) @ W + b ----------------
__global__ __launch_bounds__(256) void lk_node(
    const float* __restrict__ acc, const float* __restrict__ cnt,
    const float* __restrict__ W, const float* __restrict__ b,
    float* __restrict__ Y, int R)
{
    __shared__ float ws[256];
    __shared__ float bs[16];
    const int tid = threadIdx.x;
    ws[tid] = W[tid];
    if (tid < 16) bs[tid] = b[tid];
    __syncthreads();
    const int row = blockIdx.x * 256 + tid;
    if (row >= R) return;

    const float* ap = acc + (size_t)row * 16;
    float rc = 1.0f / fmaxf(cnt[row], 1.0f);
    float x[16];
#pragma unroll
    for (int k4 = 0; k4 < 16; k4 += 4) {
        float4 v = *(const float4*)(ap + k4);
        x[k4 + 0] = LRELU(v.x * rc); x[k4 + 1] = LRELU(v.y * rc);
        x[k4 + 2] = LRELU(v.z * rc); x[k4 + 3] = LRELU(v.w * rc);
    }
    float y[16];
#pragma unroll
    for (int n = 0; n < 16; n++) y[n] = bs[n];
#pragma unroll
    for (int k = 0; k < 16; k++) {
        float xv = x[k];
#pragma unroll
        for (int n4 = 0; n4 < 16; n4 += 4) {
            float4 w = *(const float4*)(ws + k * 16 + n4);
            y[n4 + 0] += xv * w.x; y[n4 + 1] += xv * w.y;
            y[n4 + 2] += xv * w.z; y[n4 + 3] += xv * w.w;
        }
    }
    float* yp = Y + (size_t)row * 16;
#pragma unroll
    for (int n4 = 0; n4 < 16; n4 += 4)
        *(float4*)(yp + n4) = make_float4(y[n4], y[n4 + 1], y[n4 + 2], y[n4 + 3]);
}

// ---------------- K=16 txn transform (layer 1): in-place h_t + atomic scatter ----------------
__global__ __launch_bounds__(256) void lk_txn(
    float* __restrict__ h_t, const float* __restrict__ W, const float* __restrict__ b,
    const float* __restrict__ tmp_c, const float* __restrict__ tmp_m,
    const int* __restrict__ card_idx, const int* __restrict__ merch_idx,
    float* __restrict__ acc_c, float* __restrict__ acc_m)
{
    __shared__ float ws[16 * 48];
    __shared__ float bs[48];
    const int tid = threadIdx.x;
    for (int i = tid; i < 768; i += 256) {
        int k = i / 48, c = i % 48, e = c >> 4, n = c & 15;
        ws[i] = W[(2 + e) * 256 + k * 16 + n];
    }
    if (tid < 48) { int e = tid >> 4, n = tid & 15; bs[tid] = b[(2 + e) * 16 + n]; }
    __syncthreads();
    const int row = blockIdx.x * 256 + tid;
    if (row >= NTXN) return;

    float* hp = h_t + (size_t)row * 16;
    float x[16];
#pragma unroll
    for (int k4 = 0; k4 < 16; k4 += 4) {
        float4 v = *(const float4*)(hp + k4);
        x[k4 + 0] = LRELU(v.x); x[k4 + 1] = LRELU(v.y);
        x[k4 + 2] = LRELU(v.z); x[k4 + 3] = LRELU(v.w);
    }
    float acc[48];
#pragma unroll
    for (int n = 0; n < 48; n++) acc[n] = bs[n];
#pragma unroll
    for (int k = 0; k < 16; k++) {
        float xv = x[k];
#pragma unroll
        for (int n4 = 0; n4 < 48; n4 += 4) {
            float4 w = *(const float4*)(ws + k * 48 + n4);
            acc[n4 + 0] += xv * w.x; acc[n4 + 1] += xv * w.y;
            acc[n4 + 2] += xv * w.z; acc[n4 + 3] += xv * w.w;
        }
    }
    const int ci = card_idx[row], mi = merch_idx[row];
    const float* cp = tmp_c + (size_t)ci * 16;
    const float* mp = tmp_m + (size_t)mi * 16;
#pragma unroll
    for (int n4 = 0; n4 < 16; n4 += 4) {
        float4 cv = *(const float4*)(cp + n4);
        float4 mv = *(const float4*)(mp + n4);
        float4 o = make_float4(acc[n4] + cv.x + mv.x, acc[n4 + 1] + cv.y + mv.y,
                               acc[n4 + 2] + cv.z + mv.z, acc[n4 + 3] + cv.w + mv.w);
        *(float4*)(hp + n4) = o;
    }
    float* ac = acc_c + (size_t)ci * 16;
    float* am = acc_m + (size_t)mi * 16;
#pragma unroll
    for (int n = 0; n < 16; n++) atomicAdd(ac + n, acc[16 + n]);
#pragma unroll
    for (int n = 0; n < 16; n++) atomicAdd(am + n, acc[32 + n]);
}

// ---------------- Layer 2 txn + output head (segment means of layer 2 are dead code) ----------------
__global__ __launch_bounds__(256) void lk_out(
    const float* __restrict__ h_t, const float* __restrict__ W2, const float* __restrict__ b2,
    const float* __restrict__ W_out, const float* __restrict__ b_out,
    const float* __restrict__ tmp_c, const float* __restrict__ tmp_m,
    const int* __restrict__ card_idx, const int* __restrict__ merch_idx,
    float* __restrict__ out)
{
    __shared__ float ws[256];   // W2[e=2] (self)
    __shared__ float bs[16];
    __shared__ float wo[32];
    __shared__ float bo[2];
    const int tid = threadIdx.x;
    ws[tid] = W2[2 * 256 + tid];
    if (tid < 16) bs[tid] = b2[2 * 16 + tid];
    if (tid < 32) wo[tid] = W_out[tid];
    if (tid < 2) bo[tid] = b_out[tid];
    __syncthreads();
    const int row = blockIdx.x * 256 + tid;
    if (row >= NTXN) return;

    const float* hp = h_t + (size_t)row * 16;
    float x[16];
#pragma unroll
    for (int k4 = 0; k4 < 16; k4 += 4) {
        float4 v = *(const float4*)(hp + k4);
        x[k4 + 0] = LRELU(v.x); x[k4 + 1] = LRELU(v.y);
        x[k4 + 2] = LRELU(v.z); x[k4 + 3] = LRELU(v.w);
    }
    float y[16];
#pragma unroll
    for (int n = 0; n < 16; n++) y[n] = bs[n];
#pragma unroll
    for (int k = 0; k < 16; k++) {
        float xv = x[k];
#pragma unroll
        for (int n4 = 0; n4 < 16; n4 += 4) {
            float4 w = *(const float4*)(ws + k * 16 + n4);
            y[n4 + 0] += xv * w.x; y[n4 + 1] += xv * w.y;
            y[n4 + 2] += xv * w.z; y[n4 + 3] += xv * w.w;
        }
    }
    const int ci = card_idx[row], mi = merch_idx[row];
    const float* cp = tmp_c + (size_t)ci * 16;
    const float* mp = tmp_m + (size_t)mi * 16;
    float o0 = bo[0], o1 = bo[1];
#pragma unroll
    for (int n4 = 0; n4 < 16; n4 += 4) {
        float4 cv = *(const float4*)(cp + n4);
        float4 mv = *(const float4*)(mp + n4);
        float t0 = y[n4 + 0] + cv.x + mv.x;
        float t1 = y[n4 + 1] + cv.y + mv.y;
        float t2 = y[n4 + 2] + cv.z + mv.z;
        float t3 = y[n4 + 3] + cv.w + mv.w;
        o0 += t0 * wo[(n4 + 0) * 2] + t1 * wo[(n4 + 1) * 2] + t2 * wo[(n4 + 2) * 2] + t3 * wo[(n4 + 3) * 2];
        o1 += t0 * wo[(n4 + 0) * 2 + 1] + t1 * wo[(n4 + 1) * 2 + 1] + t2 * wo[(n4 + 2) * 2 + 1] + t3 * wo[(n4 + 3) * 2 + 1];
    }
    *(float2*)(out + (size_t)row * 2) = make_float2(o0, o1);
}

extern "C" void kernel_launch(void* const* d_in, const int* in_sizes, int n_in,
                              void* d_out, int out_size, void* d_ws, size_t ws_size,
                              hipStream_t stream)
{
    const float* feats     = (const float*)d_in[0];
    const float* emb_card  = (const float*)d_in[1];
    const float* emb_merch = (const float*)d_in[2];
    const float* W0        = (const float*)d_in[3];
    const float* b0        = (const float*)d_in[4];
    const float* W1        = (const float*)d_in[5];
    const float* b1        = (const float*)d_in[6];
    const float* W2        = (const float*)d_in[7];
    const float* b2        = (const float*)d_in[8];
    const float* W_out     = (const float*)d_in[9];
    const float* b_out     = (const float*)d_in[10];
    const int*   card_idx  = (const int*)d_in[11];
    const int*   merch_idx = (const int*)d_in[12];
    float* out = (float*)d_out;
    float* ws  = (float*)d_ws;

    // d_ws layout (floats): contiguous so the scatter accumulators memset in one shot
    float* acc_c = ws;                       //  8,000,000  (500K x 16)
    float* acc_m = ws + 8000000;             //  1,600,000  (100K x 16)
    float* cnt_c = ws + 9600000;             //    500,000
    float* cnt_m = ws + 10100000;            //    100,000
    float* h_t   = ws + 10200000;            // 16,000,000  (1M x 16)
    float* tmp_c = ws + 26200000;            //  8,000,000
    float* tmp_m = ws + 34200000;            //  1,600,000  -> total 35.8M floats = 143.2 MB

    const int GB_TXN   = (NTXN   + 255) / 256;  // 3907
    const int GB_CARD  = (NCARD  + 255) / 256;  // 1954
    const int GB_MERCH = (NMERCH + 255) / 256;  // 391

    // zero accumulators + counts (acc_c..cnt_m contiguous)
    hipMemsetAsync(acc_c, 0, (size_t)10200000 * sizeof(float), stream);

    // ---- Layer 0 (K=128) ----
    k128_node<<<GB_CARD,  256, 0, stream>>>(emb_card,  W0 + 0 * 2048, b0 + 0,  tmp_c, NCARD);
    k128_node<<<GB_MERCH, 256, 0, stream>>>(emb_merch, W0 + 1 * 2048, b0 + 16, tmp_m, NMERCH);
    k128_txn<<<GB_TXN, 256, 0, stream>>>(feats, W0, b0, tmp_c, tmp_m, card_idx, merch_idx,
                                         h_t, acc_c, acc_m, cnt_c, cnt_m);

    // ---- Layer 1 (K=16) ----
    lk_node<<<GB_CARD,  256, 0, stream>>>(acc_c, cnt_c, W1 + 0 * 256, b1 + 0,  tmp_c, NCARD);
    lk_node<<<GB_MERCH, 256, 0, stream>>>(acc_m, cnt_m, W1 + 1 * 256, b1 + 16, tmp_m, NMERCH);
    hipMemsetAsync(acc_c, 0, (size_t)9600000 * sizeof(float), stream);   // acc only; counts persist
    lk_txn<<<GB_TXN, 256, 0, stream>>>(h_t, W1, b1, tmp_c, tmp_m, card_idx, merch_idx, acc_c, acc_m);

    // ---- Layer 2 (K=16) + output head ----
    lk_node<<<GB_CARD,  256, 0, stream>>>(acc_c, cnt_c, W2 + 0 * 256, b2 + 0,  tmp_c, NCARD);
    lk_node<<<GB_MERCH, 256, 0, stream>>>(acc_m, cnt_m, W2 + 1 * 256, b2 + 16, tmp_m, NMERCH);
    lk_out<<<GB_TXN, 256, 0, stream>>>(h_t, W2, b2, W_out, b_out, tmp_c, tmp_m,
                                       card_idx, merch_idx, out);
}